// Round 7
// baseline (484.689 us; speedup 1.0000x reference)
//
#include <hip/hip_runtime.h>
#include <hip/hip_bf16.h>
#include <stdint.h>

// ---------------------------------------------------------------------------
// GCN forward: 3 layers of  out = Ahat * (X @ W) + b, relu between layers.
// Factored normalization: out[d] = dinv[d]*( sum_{s in in(d)} H'[s] + H'[d] ) + b
// where H'[i] = bf16( dinv[i] * (X@W)[i] ).
// GEMM: MFMA bf16 hi/lo split (3 mfma per product -> ~fp32 precision).
// CSR build: VIRTUAL-SHARD dst-range partitioning. Block b = shard (b&7),
// chunk (b>>3); shard v handles only dst in [v*NS,(v+1)*NS). With round-robin
// dispatch each shard's atomics + col_idx writes stay in one XCD's L2 (no
// cross-XCD dirty-line ping-pong). Correct for ANY block->XCD mapping.
// Aggregation: wave-per-node split-wave u64 gather, zero-row padding.
// ---------------------------------------------------------------------------

typedef __attribute__((ext_vector_type(8))) short bf16x8;
typedef __attribute__((ext_vector_type(4))) float f32x4;

__device__ __forceinline__ float bflo(uint32_t u) { return __uint_as_float(u << 16); }
__device__ __forceinline__ float bfhi(uint32_t u) { return __uint_as_float(u & 0xffff0000u); }
__device__ __forceinline__ unsigned short f2bf(float f) {
    uint32_t x = __float_as_uint(f);
    return (unsigned short)((x + 0x7fffu + ((x >> 16) & 1u)) >> 16);
}

#define EDGES_PER_CHUNK 4096

// sharded degree count: shard v counts only its dst range (atomics XCD-local)
__global__ __launch_bounds__(256) void k_deg(const int* __restrict__ dst,
                                             int* __restrict__ deg,
                                             int NS, int E) {
    int v = blockIdx.x & 7;
    int base = (blockIdx.x >> 3) * EDGES_PER_CHUNK;
    int lo = v * NS, hi = lo + NS;
#pragma unroll
    for (int i = 0; i < EDGES_PER_CHUNK / 256; ++i) {
        int e = base + i * 256 + threadIdx.x;
        if (e < E) {
            int d = dst[e];
            if (d >= lo && d < hi) atomicAdd(&deg[d], 1);
        }
    }
}

// ---- hierarchical scan: 1024 elements per block ---------------------------
__global__ __launch_bounds__(256) void k_scan_local(const int* __restrict__ deg,
                                                    int* __restrict__ incl,
                                                    int* __restrict__ bsum, int N) {
    __shared__ int part[256];
    int t = threadIdx.x;
    int idx0 = blockIdx.x * 1024 + t * 4;
    int4 lv = {0, 0, 0, 0};
    if (idx0 + 4 <= N) {
        lv = *(const int4*)&deg[idx0];
    } else {
        int* pv = (int*)&lv;
        for (int i = 0; i < 4; ++i) pv[i] = (idx0 + i < N) ? deg[idx0 + i] : 0;
    }
    int s = lv.x + lv.y + lv.z + lv.w;
    part[t] = s;
    __syncthreads();
    for (int off = 1; off < 256; off <<= 1) {
        int x = (t >= off) ? part[t - off] : 0;
        __syncthreads();
        part[t] += x;
        __syncthreads();
    }
    int run = (t == 0) ? 0 : part[t - 1];
    if (t == 255) bsum[blockIdx.x] = part[255];
    int4 ov;
    ov.x = run + lv.x;
    ov.y = ov.x + lv.y;
    ov.z = ov.y + lv.z;
    ov.w = ov.z + lv.w;
    if (idx0 + 4 <= N) {
        *(int4*)&incl[idx0] = ov;
    } else {
        int* po = (int*)&ov;
        for (int i = 0; i < 4; ++i)
            if (idx0 + i < N) incl[idx0 + i] = po[i];
    }
}

// exclusive scan of up to 256 block sums; also writes row_ptr[N] = total
__global__ __launch_bounds__(256) void k_scan_tops(int* __restrict__ bsum, int nb,
                                                   int* __restrict__ row_ptr, int N) {
    __shared__ int part[256];
    int t = threadIdx.x;
    int v = (t < nb) ? bsum[t] : 0;
    part[t] = v;
    __syncthreads();
    for (int off = 1; off < 256; off <<= 1) {
        int x = (t >= off) ? part[t - off] : 0;
        __syncthreads();
        part[t] += x;
        __syncthreads();
    }
    if (t < nb) bsum[t] = part[t] - v;   // exclusive
    if (t == 255) row_ptr[N] = part[255];
}

// row_ptr + dinv + zero-row init (fused)
__global__ __launch_bounds__(256) void k_scan_final(const int* __restrict__ incl,
                                                    const int* __restrict__ deg,
                                                    const int* __restrict__ bsum,
                                                    int* __restrict__ row_ptr,
                                                    float* __restrict__ dinv,
                                                    unsigned short* __restrict__ hzero,
                                                    int N) {
    int i = blockIdx.x * 256 + threadIdx.x;
    if (blockIdx.x == 0 && threadIdx.x < 16) {
        uint4 z; z.x = 0; z.y = 0; z.z = 0; z.w = 0;
        ((uint4*)hzero)[threadIdx.x] = z;
    }
    if (i < N) {
        int dg = deg[i];
        row_ptr[i] = incl[i] - dg + bsum[i >> 10];
        dinv[i] = rsqrtf((float)(dg + 1));  // +1 self-loop
    }
}

// sharded scatter: cursor atomics + col_idx writes are shard(=XCD)-local
__global__ __launch_bounds__(256) void k_scatter(const int* __restrict__ src,
                                                 const int* __restrict__ dst,
                                                 const int* __restrict__ row_ptr,
                                                 int* __restrict__ cursor,
                                                 int* __restrict__ col_idx,
                                                 int NS, int E) {
    int v = blockIdx.x & 7;
    int base = (blockIdx.x >> 3) * EDGES_PER_CHUNK;
    int lo = v * NS, hi = lo + NS;
#pragma unroll
    for (int i = 0; i < EDGES_PER_CHUNK / 256; ++i) {
        int e = base + i * 256 + threadIdx.x;
        if (e < E) {
            int d = dst[e];
            if (d >= lo && d < hi) {
                int pos = row_ptr[d] + atomicAdd(&cursor[d], 1);
                col_idx[pos] = src[e];
            }
        }
    }
}

// W [K][M] f32 -> Wt_hi[c][k], Wt_lo[c][k] bf16 (transposed, hi plane then lo)
__global__ __launch_bounds__(256) void k_prepw(const float* __restrict__ W0,
                                               const float* __restrict__ W1,
                                               const float* __restrict__ W2,
                                               unsigned short* __restrict__ wt0,
                                               unsigned short* __restrict__ wt1,
                                               unsigned short* __restrict__ wt2) {
    int id = blockIdx.x * 256 + threadIdx.x;
    const float* Wsrc;
    unsigned short* dst;
    int t, M, plane;
    if (id < 16384)      { t = id;         Wsrc = W0; dst = wt0; M = 128; plane = 16384; }
    else if (id < 32768) { t = id - 16384; Wsrc = W1; dst = wt1; M = 128; plane = 16384; }
    else if (id < 40960) { t = id - 32768; Wsrc = W2; dst = wt2; M = 64;  plane = 8192;  }
    else return;
    int k = (M == 128) ? (t >> 7) : (t >> 6);
    int c = (M == 128) ? (t & 127) : (t & 63);
    float v = Wsrc[k * M + c];
    unsigned short hi = f2bf(v);
    float lov = v - bflo((uint32_t)hi);
    dst[c * 128 + k]         = hi;
    dst[plane + c * 128 + k] = f2bf(lov);
}

// H[r,:] = bf16( dinv[r] * (A[r,:] @ W) ) via split-bf16 MFMA.
// A f32 [N,128]; Wt = transposed hi/lo bf16 [NCOL][128] x2; H bf16 [N,NCOL].
// Block: 256 thr / 4 waves, tile 128 rows x NCOL cols, K-tiled by 64.
template <int NCOL>
__global__ __launch_bounds__(256) void k_gemm_mfma(
    const float* __restrict__ A, const unsigned short* __restrict__ Wt,
    const float* __restrict__ dinv, unsigned short* __restrict__ H, int N) {
    constexpr int K = 128, KT = 64;
    constexpr int A_PLANE = 128 * KT;     // shorts
    constexpr int W_PLANE = NCOL * KT;
    __shared__ __align__(16) unsigned short sm[2 * A_PLANE + 2 * W_PLANE];  // 64/48 KB
    unsigned short* Ah  = sm;
    unsigned short* Al  = sm + A_PLANE;
    unsigned short* Whp = sm + 2 * A_PLANE;
    unsigned short* Wlp = sm + 2 * A_PLANE + W_PLANE;

    const int tid = threadIdx.x;
    const long r0 = (long)blockIdx.x * 128;
    const int w = tid >> 6, l = tid & 63;
    const int lr = l & 15, lk = l >> 4;
    constexpr int WR = (NCOL == 128) ? 4 : 2;          // 16-row frags per wave
    const int wrow = (NCOL == 128) ? (w >> 1) * 64 : w * 32;
    const int wcol = (NCOL == 128) ? (w & 1) * 64 : 0;

    f32x4 acc[WR][4];
#pragma unroll
    for (int i = 0; i < WR; ++i)
#pragma unroll
        for (int j = 0; j < 4; ++j) acc[i][j] = (f32x4){0.f, 0.f, 0.f, 0.f};

    for (int kt = 0; kt < 2; ++kt) {
        if (kt) __syncthreads();           // previous compute done
        // ---- stage A tile: 128 rows x 64 k, f32 -> hi/lo bf16, swizzled ----
#pragma unroll
        for (int it = 0; it < 4; ++it) {
            int id = it * 256 + tid;
            int r = id >> 3, kc = id & 7;   // 8 chunks of 8 f32 per row
            long gr = r0 + r;
            if (gr >= N) gr = N - 1;
            const float* ap = &A[gr * K + kt * KT + kc * 8];
            float4 v0 = *(const float4*)ap;
            float4 v1 = *(const float4*)(ap + 4);
            float vv[8] = {v0.x, v0.y, v0.z, v0.w, v1.x, v1.y, v1.z, v1.w};
            union { unsigned short u[8]; bf16x8 v; } ph, pl;
#pragma unroll
            for (int j = 0; j < 8; ++j) {
                unsigned short h = f2bf(vv[j]);
                ph.u[j] = h;
                pl.u[j] = f2bf(vv[j] - bflo((uint32_t)h));
            }
            int boff = r * 128 + ((kc * 16) ^ ((r & 7) << 4));
            *(bf16x8*)((char*)Ah + boff) = ph.v;
            *(bf16x8*)((char*)Al + boff) = pl.v;
        }
        // ---- stage W tile: NCOL rows x 64 k, hi+lo, swizzled ----
#pragma unroll
        for (int it = 0; it < NCOL / 32; ++it) {
            int id = it * 256 + tid;
            int c = id >> 3, kc = id & 7;
            const unsigned short* wp = &Wt[c * K + kt * KT + kc * 8];
            bf16x8 vh = *(const bf16x8*)wp;
            bf16x8 vl = *(const bf16x8*)(wp + NCOL * K);
            int boff = c * 128 + ((kc * 16) ^ ((c & 7) << 4));
            *(bf16x8*)((char*)Whp + boff) = vh;
            *(bf16x8*)((char*)Wlp + boff) = vl;
        }
        __syncthreads();
        // ---- compute: 2 k-steps of 32 ----
#pragma unroll
        for (int ks = 0; ks < 2; ++ks) {
            int kb = ks * 64 + lk * 16;
            bf16x8 bh[4], bl[4];
#pragma unroll
            for (int cf = 0; cf < 4; ++cf) {
                int c = wcol + cf * 16 + lr;
                int off = c * 128 + (kb ^ ((c & 7) << 4));
                bh[cf] = *(bf16x8*)((char*)Whp + off);
                bl[cf] = *(bf16x8*)((char*)Wlp + off);
            }
#pragma unroll
            for (int rf = 0; rf < WR; ++rf) {
                int r = wrow + rf * 16 + lr;
                int off = r * 128 + (kb ^ ((r & 7) << 4));
                bf16x8 ah = *(bf16x8*)((char*)Ah + off);
                bf16x8 al = *(bf16x8*)((char*)Al + off);
#pragma unroll
                for (int cf = 0; cf < 4; ++cf) {
                    acc[rf][cf] = __builtin_amdgcn_mfma_f32_16x16x32_bf16(ah, bh[cf], acc[rf][cf], 0, 0, 0);
                    acc[rf][cf] = __builtin_amdgcn_mfma_f32_16x16x32_bf16(al, bh[cf], acc[rf][cf], 0, 0, 0);
                    acc[rf][cf] = __builtin_amdgcn_mfma_f32_16x16x32_bf16(ah, bl[cf], acc[rf][cf], 0, 0, 0);
                }
            }
        }
    }
    // ---- epilogue: C frag (col=lane&15, row=(lane>>4)*4+reg), scale, bf16 ----
#pragma unroll
    for (int rf = 0; rf < WR; ++rf) {
        long rb = r0 + wrow + rf * 16 + lk * 4;
#pragma unroll
        for (int reg = 0; reg < 4; ++reg) {
            long r = rb + reg;
            if (r < N) {
                float dv = dinv[r];
#pragma unroll
                for (int cf = 0; cf < 4; ++cf) {
                    int c = wcol + cf * 16 + lr;
                    H[r * NCOL + c] = f2bf(dv * acc[rf][cf][reg]);
                }
            }
        }
    }
}

// One wave per node, split halves: lanes 0-31 = even edge, 32-63 = odd edge.
// F=128: lane owns 4 features (u64 gather); F=64: 2 features (u32 gather).
// Tail edges padded with DUMMY index -> zero row (no branches in inner loop).
template <int F, bool RELU>
__global__ __launch_bounds__(256) void k_agg(const unsigned short* __restrict__ H,
                                             const int* __restrict__ row_ptr,
                                             const int* __restrict__ col_idx,
                                             const float* __restrict__ dinv,
                                             const float* __restrict__ bias,
                                             float* __restrict__ Y, int N) {
    constexpr int FL = F / 32;          // floats per lane: 4 (F=128) / 2 (F=64)
    int lane = threadIdx.x & 63;
    int node = blockIdx.x * 4 + (threadIdx.x >> 6);
    if (node >= N) return;
    const int half = lane >> 5, hl = lane & 31;
    const int DUMMY = (F == 128) ? N : 2 * N;   // both map to the zero row

    float acc[FL];
    if constexpr (F == 128) {
        if (half == 0) {
            uint64_t u = *(const uint64_t*)&H[(size_t)node * 128 + hl * 4];
            acc[0] = bflo((uint32_t)u);         acc[1] = bfhi((uint32_t)u);
            acc[2] = bflo((uint32_t)(u >> 32)); acc[3] = bfhi((uint32_t)(u >> 32));
        } else { acc[0] = acc[1] = acc[2] = acc[3] = 0.f; }
    } else {
        if (half == 0) {
            uint32_t u = *(const uint32_t*)&H[(size_t)node * 64 + hl * 2];
            acc[0] = bflo(u); acc[1] = bfhi(u);
        } else { acc[0] = acc[1] = 0.f; }
    }

    int start = row_ptr[node], end = row_ptr[node + 1];
    for (int base = start; base < end; base += 64) {
        int idx = DUMMY;
        if (base + lane < end) idx = col_idx[base + lane];
        int cnt = min(64, end - base);
        for (int j = 0; j < cnt; j += 8) {      // 8 edges per iter (2 per pass)
            int s0 = __shfl(idx, j + half);
            int s1 = __shfl(idx, j + 2 + half);
            int s2 = __shfl(idx, j + 4 + half);
            int s3 = __shfl(idx, j + 6 + half);
            if constexpr (F == 128) {
                uint64_t u0 = *(const uint64_t*)&H[(size_t)s0 * 128 + hl * 4];
                uint64_t u1 = *(const uint64_t*)&H[(size_t)s1 * 128 + hl * 4];
                uint64_t u2 = *(const uint64_t*)&H[(size_t)s2 * 128 + hl * 4];
                uint64_t u3 = *(const uint64_t*)&H[(size_t)s3 * 128 + hl * 4];
                acc[0] += bflo((uint32_t)u0);         acc[1] += bfhi((uint32_t)u0);
                acc[2] += bflo((uint32_t)(u0 >> 32)); acc[3] += bfhi((uint32_t)(u0 >> 32));
                acc[0] += bflo((uint32_t)u1);         acc[1] += bfhi((uint32_t)u1);
                acc[2] += bflo((uint32_t)(u1 >> 32)); acc[3] += bfhi((uint32_t)(u1 >> 32));
                acc[0] += bflo((uint32_t)u2);         acc[1] += bfhi((uint32_t)u2);
                acc[2] += bflo((uint32_t)(u2 >> 32)); acc[3] += bfhi((uint32_t)(u2 >> 32));
                acc[0] += bflo((uint32_t)u3);         acc[1] += bfhi((uint32_t)u3);
                acc[2] += bflo((uint32_t)(u3 >> 32)); acc[3] += bfhi((uint32_t)(u3 >> 32));
            } else {
                uint32_t u0 = *(const uint32_t*)&H[(size_t)s0 * 64 + hl * 2];
                uint32_t u1 = *(const uint32_t*)&H[(size_t)s1 * 64 + hl * 2];
                uint32_t u2 = *(const uint32_t*)&H[(size_t)s2 * 64 + hl * 2];
                uint32_t u3 = *(const uint32_t*)&H[(size_t)s3 * 64 + hl * 2];
                acc[0] += bflo(u0); acc[1] += bfhi(u0);
                acc[0] += bflo(u1); acc[1] += bfhi(u1);
                acc[0] += bflo(u2); acc[1] += bfhi(u2);
                acc[0] += bflo(u3); acc[1] += bfhi(u3);
            }
        }
    }

    // combine halves: lane<32 gets lane+32's partial, writes result
    float part[FL];
#pragma unroll
    for (int f = 0; f < FL; ++f) part[f] = __shfl_xor(acc[f], 32);
    if (half == 0) {
        float dv = dinv[node];
        if constexpr (F == 128) {
            float4 b = *(const float4*)&bias[hl * 4];
            float4 o;
            o.x = dv * (acc[0] + part[0]) + b.x;
            o.y = dv * (acc[1] + part[1]) + b.y;
            o.z = dv * (acc[2] + part[2]) + b.z;
            o.w = dv * (acc[3] + part[3]) + b.w;
            if (RELU) {
                o.x = fmaxf(o.x, 0.f); o.y = fmaxf(o.y, 0.f);
                o.z = fmaxf(o.z, 0.f); o.w = fmaxf(o.w, 0.f);
            }
            *(float4*)&Y[(size_t)node * 128 + hl * 4] = o;
        } else {
            float2 b = *(const float2*)&bias[hl * 2];
            float2 o;
            o.x = dv * (acc[0] + part[0]) + b.x;
            o.y = dv * (acc[1] + part[1]) + b.y;
            if (RELU) { o.x = fmaxf(o.x, 0.f); o.y = fmaxf(o.y, 0.f); }
            *(float2*)&Y[(size_t)node * 64 + hl * 2] = o;
        }
    }
}

extern "C" void kernel_launch(void* const* d_in, const int* in_sizes, int n_in,
                              void* d_out, int out_size, void* d_ws, size_t ws_size,
                              hipStream_t stream) {
    const float* x  = (const float*)d_in[0];
    const int* eidx = (const int*)d_in[1];
    const float* W0 = (const float*)d_in[2];
    const float* b0 = (const float*)d_in[3];
    const float* W1 = (const float*)d_in[4];
    const float* b1 = (const float*)d_in[5];
    const float* W2 = (const float*)d_in[6];
    const float* b2 = (const float*)d_in[7];
    float* out = (float*)d_out;

    const int N = in_sizes[0] / 128;
    const int E = in_sizes[1] / 2;
    const int* srcp = eidx;
    const int* dstp = eidx + E;

    char* p = (char*)d_ws;
    auto take = [&](size_t bytes) {
        char* r = p;
        p += (bytes + 255) & ~(size_t)255;
        return r;
    };
    int*            deg     = (int*)take((size_t)N * 4);
    int*            cursor  = (int*)take((size_t)N * 4);
    int*            row_ptr = (int*)take((size_t)(N + 1) * 4);
    float*          dinv    = (float*)take((size_t)N * 4);
    int*            col_idx = (int*)take((size_t)E * 4);
    unsigned short* hbuf    = (unsigned short*)take((size_t)(N + 1) * 128 * 2);
    float*          ybuf    = (float*)take((size_t)N * 128 * 4);
    int*            incl    = (int*)take((size_t)N * 4);
    int*            bsum    = (int*)take((size_t)256 * 4);
    unsigned short* wt0     = (unsigned short*)take((size_t)2 * 16384 * 2);
    unsigned short* wt1     = (unsigned short*)take((size_t)2 * 16384 * 2);
    unsigned short* wt2     = (unsigned short*)take((size_t)2 * 8192 * 2);

    hipMemsetAsync(deg, 0, (size_t)N * 4, stream);
    hipMemsetAsync(cursor, 0, (size_t)N * 4, stream);

    const int NS = (N + 7) / 8;                          // nodes per shard
    const int nch = (E + EDGES_PER_CHUNK - 1) / EDGES_PER_CHUNK;

    k_deg<<<8 * nch, 256, 0, stream>>>(dstp, deg, NS, E);
    k_prepw<<<160, 256, 0, stream>>>(W0, W1, W2, wt0, wt1, wt2);

    int nb = (N + 1023) / 1024;  // 98 for N=100000 (must be <= 256)
    k_scan_local<<<nb, 256, 0, stream>>>(deg, incl, bsum, N);
    k_scan_tops<<<1, 256, 0, stream>>>(bsum, nb, row_ptr, N);
    k_scan_final<<<(N + 255) / 256, 256, 0, stream>>>(incl, deg, bsum, row_ptr,
                                                      dinv, hbuf + (size_t)N * 128, N);

    k_scatter<<<8 * nch, 256, 0, stream>>>(srcp, dstp, row_ptr, cursor,
                                           col_idx, NS, E);

    int gemm_grid = (N + 127) / 128;
    int agg_grid  = (N + 3) / 4;

    // layer 0: h' = dinv*(x@W0) ; y = dinv*(sum h') + b0 ; relu
    k_gemm_mfma<128><<<gemm_grid, 256, 0, stream>>>(x, wt0, dinv, hbuf, N);
    k_agg<128, true><<<agg_grid, 256, 0, stream>>>(hbuf, row_ptr, col_idx,
                                                   dinv, b0, ybuf, N);
    // layer 1
    k_gemm_mfma<128><<<gemm_grid, 256, 0, stream>>>(ybuf, wt1, dinv, hbuf, N);
    k_agg<128, true><<<agg_grid, 256, 0, stream>>>(hbuf, row_ptr, col_idx,
                                                   dinv, b1, ybuf, N);
    // layer 2 (64-wide, no relu, straight to d_out)
    k_gemm_mfma<64><<<gemm_grid, 256, 0, stream>>>(ybuf, wt2, dinv, hbuf, N);
    k_agg<64, false><<<agg_grid, 256, 0, stream>>>(hbuf, row_ptr, col_idx,
                                                   dinv, b2, out, N);
}

// Round 8
// 394.878 us; speedup vs baseline: 1.2274x; 1.2274x over previous
//
#include <hip/hip_runtime.h>
#include <hip/hip_bf16.h>
#include <stdint.h>

// ---------------------------------------------------------------------------
// GCN forward: 3 layers of  out = Ahat * (X @ W) + b, relu between layers.
// Factored normalization: out[d] = dinv[d]*( sum_{s in in(d)} H'[s] + H'[d] ) + b
// where H'[i] = bf16( dinv[i] * (X@W)[i] ).
// GEMM: MFMA bf16 hi/lo split (3 mfma per product -> ~fp32 precision).
// CSR build: deterministic two-level counting sort, ZERO global atomics:
//   per-(chunk,bin) LDS histogram -> per-bin scan over chunks -> bin offsets
//   -> scatter to precomputed contiguous slots (write-combined) -> per-bin
//   LDS deg+scan emits row_ptr/dinv -> per-bin CSR fill (LDS cursors).
// No reliance on block->XCD mapping (R7 lesson: that mapping is undefined).
// Aggregation: wave-per-node split-wave u64 gather, zero-row padding.
// ---------------------------------------------------------------------------

typedef __attribute__((ext_vector_type(8))) short bf16x8;
typedef __attribute__((ext_vector_type(4))) float f32x4;

__device__ __forceinline__ float bflo(uint32_t u) { return __uint_as_float(u << 16); }
__device__ __forceinline__ float bfhi(uint32_t u) { return __uint_as_float(u & 0xffff0000u); }
__device__ __forceinline__ unsigned short f2bf(float f) {
    uint32_t x = __float_as_uint(f);
    return (unsigned short)((x + 0x7fffu + ((x >> 16) & 1u)) >> 16);
}

#define CE   4096   // edges per chunk
#define BINW 256    // nodes per bin

// per-chunk per-bin histogram (LDS only; fully overwrites cnt -> no memset)
__global__ __launch_bounds__(256) void k_binhist(const int* __restrict__ dst,
                                                 int* __restrict__ cnt,
                                                 int NBIN, int E) {
    extern __shared__ int h[];
    int c = blockIdx.x, base = c * CE;
    for (int i = threadIdx.x; i < NBIN; i += 256) h[i] = 0;
    __syncthreads();
    for (int i = 0; i < CE; i += 256) {
        int e = base + i + threadIdx.x;
        if (e < E) atomicAdd(&h[dst[e] >> 8], 1);
    }
    __syncthreads();
    for (int i = threadIdx.x; i < NBIN; i += 256) cnt[c * NBIN + i] = h[i];
}

// per-bin exclusive scan over chunks: off_cb[c][b], tot[b]
__global__ __launch_bounds__(256) void k_colscan(const int* __restrict__ cnt,
                                                 int* __restrict__ off_cb,
                                                 int* __restrict__ tot,
                                                 int NBIN, int NCHUNK) {
    __shared__ int part[256];
    int b = blockIdx.x, t = threadIdx.x;
    int K = (NCHUNK + 255) >> 8;
    int c0 = t * K;
    int vals[16];                       // K <= 16 (E <= 16.7M)
    int s = 0;
    for (int k = 0; k < K; ++k) {
        int c = c0 + k;
        int v = (c < NCHUNK) ? cnt[c * NBIN + b] : 0;
        vals[k] = s;                    // thread-local exclusive prefix
        s += v;
    }
    part[t] = s;
    __syncthreads();
    for (int off = 1; off < 256; off <<= 1) {
        int x = (t >= off) ? part[t - off] : 0;
        __syncthreads();
        part[t] += x;
        __syncthreads();
    }
    int run = (t == 0) ? 0 : part[t - 1];
    for (int k = 0; k < K; ++k) {
        int c = c0 + k;
        if (c < NCHUNK) off_cb[c * NBIN + b] = run + vals[k];
    }
    if (t == 255) tot[b] = part[255];
}

// scan bin totals -> bin_off; also zero agg dummy row, row_ptr[N]=E
__global__ __launch_bounds__(512) void k_binoff(const int* __restrict__ tot,
                                                int* __restrict__ bin_off,
                                                int* __restrict__ row_ptr,
                                                unsigned short* __restrict__ hzero,
                                                int NBIN, int N, int E) {
    __shared__ int part[512];
    int t = threadIdx.x;
    int v = (t < NBIN) ? tot[t] : 0;
    part[t] = v;
    __syncthreads();
    for (int off = 1; off < 512; off <<= 1) {
        int x = (t >= off) ? part[t - off] : 0;
        __syncthreads();
        part[t] += x;
        __syncthreads();
    }
    if (t < NBIN) bin_off[t] = part[t] - v;     // exclusive
    if (t == 0) { bin_off[NBIN] = E; row_ptr[N] = E; }
    if (t < 16) { uint4 z; z.x = z.y = z.z = z.w = 0; ((uint4*)hzero)[t] = z; }
}

// scatter edges into bin-sorted order at precomputed slots (LDS cursors only).
// pack = (d & 255) << 24 | src   (src < 2^24)
__global__ __launch_bounds__(256) void k_binscatter(const int* __restrict__ src,
                                                    const int* __restrict__ dst,
                                                    const int* __restrict__ off_cb,
                                                    const int* __restrict__ bin_off,
                                                    unsigned int* __restrict__ bpack,
                                                    int NBIN, int E) {
    extern __shared__ int lcur[];
    int c = blockIdx.x, base = c * CE;
    for (int i = threadIdx.x; i < NBIN; i += 256)
        lcur[i] = off_cb[c * NBIN + i] + bin_off[i];
    __syncthreads();
    for (int i = 0; i < CE; i += 256) {
        int e = base + i + threadIdx.x;
        if (e < E) {
            int d = dst[e], s = src[e];
            int pos = atomicAdd(&lcur[d >> 8], 1);
            bpack[pos] = (unsigned)s | ((unsigned)(d & 255) << 24);
        }
    }
}

// block-per-bin: LDS deg histogram + scan -> row_ptr, dinv (no global scan!)
__global__ __launch_bounds__(256) void k_bindeg(const unsigned int* __restrict__ bpack,
                                                const int* __restrict__ bin_off,
                                                int* __restrict__ row_ptr,
                                                float* __restrict__ dinv, int N) {
    __shared__ int h[256];
    __shared__ int part[256];
    int b = blockIdx.x, t = threadIdx.x;
    int lo = b * BINW;
    h[t] = 0;
    __syncthreads();
    int s0 = bin_off[b], s1 = bin_off[b + 1];
    for (int i = s0 + t; i < s1; i += 256)
        atomicAdd(&h[bpack[i] >> 24], 1);
    __syncthreads();
    int dg = h[t];
    part[t] = dg;
    __syncthreads();
    for (int off = 1; off < 256; off <<= 1) {
        int x = (t >= off) ? part[t - off] : 0;
        __syncthreads();
        part[t] += x;
        __syncthreads();
    }
    if (lo + t < N) {
        row_ptr[lo + t] = s0 + part[t] - dg;    // bin start + in-bin excl prefix
        dinv[lo + t] = rsqrtf((float)(dg + 1)); // +1 self-loop
    }
}

// block-per-bin CSR fill: writes confined to the bin's col_idx span
__global__ __launch_bounds__(256) void k_csr(const unsigned int* __restrict__ bpack,
                                             const int* __restrict__ bin_off,
                                             const int* __restrict__ row_ptr,
                                             int* __restrict__ col_idx, int N) {
    __shared__ int lcur[256];
    int b = blockIdx.x, t = threadIdx.x;
    int lo = b * BINW;
    lcur[t] = (lo + t < N) ? row_ptr[lo + t] : 0;
    __syncthreads();
    int s0 = bin_off[b], s1 = bin_off[b + 1];
    for (int i = s0 + t; i < s1; i += 256) {
        unsigned pk = bpack[i];
        int pos = atomicAdd(&lcur[pk >> 24], 1);
        col_idx[pos] = (int)(pk & 0xFFFFFFu);
    }
}

// W [K][M] f32 -> Wt_hi[c][k], Wt_lo[c][k] bf16 (transposed, hi plane then lo)
__global__ __launch_bounds__(256) void k_prepw(const float* __restrict__ W0,
                                               const float* __restrict__ W1,
                                               const float* __restrict__ W2,
                                               unsigned short* __restrict__ wt0,
                                               unsigned short* __restrict__ wt1,
                                               unsigned short* __restrict__ wt2) {
    int id = blockIdx.x * 256 + threadIdx.x;
    const float* Wsrc;
    unsigned short* dst;
    int t, M, plane;
    if (id < 16384)      { t = id;         Wsrc = W0; dst = wt0; M = 128; plane = 16384; }
    else if (id < 32768) { t = id - 16384; Wsrc = W1; dst = wt1; M = 128; plane = 16384; }
    else if (id < 40960) { t = id - 32768; Wsrc = W2; dst = wt2; M = 64;  plane = 8192;  }
    else return;
    int k = (M == 128) ? (t >> 7) : (t >> 6);
    int c = (M == 128) ? (t & 127) : (t & 63);
    float v = Wsrc[k * M + c];
    unsigned short hi = f2bf(v);
    float lov = v - bflo((uint32_t)hi);
    dst[c * 128 + k]         = hi;
    dst[plane + c * 128 + k] = f2bf(lov);
}

// H[r,:] = bf16( dinv[r] * (A[r,:] @ W) ) via split-bf16 MFMA.
// A f32 [N,128]; Wt = transposed hi/lo bf16 [NCOL][128] x2; H bf16 [N,NCOL].
// Block: 256 thr / 4 waves, tile 128 rows x NCOL cols, K-tiled by 64.
template <int NCOL>
__global__ __launch_bounds__(256) void k_gemm_mfma(
    const float* __restrict__ A, const unsigned short* __restrict__ Wt,
    const float* __restrict__ dinv, unsigned short* __restrict__ H, int N) {
    constexpr int K = 128, KT = 64;
    constexpr int A_PLANE = 128 * KT;     // shorts
    constexpr int W_PLANE = NCOL * KT;
    __shared__ __align__(16) unsigned short sm[2 * A_PLANE + 2 * W_PLANE];  // 64/48 KB
    unsigned short* Ah  = sm;
    unsigned short* Al  = sm + A_PLANE;
    unsigned short* Whp = sm + 2 * A_PLANE;
    unsigned short* Wlp = sm + 2 * A_PLANE + W_PLANE;

    const int tid = threadIdx.x;
    const long r0 = (long)blockIdx.x * 128;
    const int w = tid >> 6, l = tid & 63;
    const int lr = l & 15, lk = l >> 4;
    constexpr int WR = (NCOL == 128) ? 4 : 2;          // 16-row frags per wave
    const int wrow = (NCOL == 128) ? (w >> 1) * 64 : w * 32;
    const int wcol = (NCOL == 128) ? (w & 1) * 64 : 0;

    f32x4 acc[WR][4];
#pragma unroll
    for (int i = 0; i < WR; ++i)
#pragma unroll
        for (int j = 0; j < 4; ++j) acc[i][j] = (f32x4){0.f, 0.f, 0.f, 0.f};

    for (int kt = 0; kt < 2; ++kt) {
        if (kt) __syncthreads();           // previous compute done
        // ---- stage A tile: 128 rows x 64 k, f32 -> hi/lo bf16, swizzled ----
#pragma unroll
        for (int it = 0; it < 4; ++it) {
            int id = it * 256 + tid;
            int r = id >> 3, kc = id & 7;   // 8 chunks of 8 f32 per row
            long gr = r0 + r;
            if (gr >= N) gr = N - 1;
            const float* ap = &A[gr * K + kt * KT + kc * 8];
            float4 v0 = *(const float4*)ap;
            float4 v1 = *(const float4*)(ap + 4);
            float vv[8] = {v0.x, v0.y, v0.z, v0.w, v1.x, v1.y, v1.z, v1.w};
            union { unsigned short u[8]; bf16x8 v; } ph, pl;
#pragma unroll
            for (int j = 0; j < 8; ++j) {
                unsigned short h = f2bf(vv[j]);
                ph.u[j] = h;
                pl.u[j] = f2bf(vv[j] - bflo((uint32_t)h));
            }
            int boff = r * 128 + ((kc * 16) ^ ((r & 7) << 4));
            *(bf16x8*)((char*)Ah + boff) = ph.v;
            *(bf16x8*)((char*)Al + boff) = pl.v;
        }
        // ---- stage W tile: NCOL rows x 64 k, hi+lo, swizzled ----
#pragma unroll
        for (int it = 0; it < NCOL / 32; ++it) {
            int id = it * 256 + tid;
            int c = id >> 3, kc = id & 7;
            const unsigned short* wp = &Wt[c * K + kt * KT + kc * 8];
            bf16x8 vh = *(const bf16x8*)wp;
            bf16x8 vl = *(const bf16x8*)(wp + NCOL * K);
            int boff = c * 128 + ((kc * 16) ^ ((c & 7) << 4));
            *(bf16x8*)((char*)Whp + boff) = vh;
            *(bf16x8*)((char*)Wlp + boff) = vl;
        }
        __syncthreads();
        // ---- compute: 2 k-steps of 32 ----
#pragma unroll
        for (int ks = 0; ks < 2; ++ks) {
            int kb = ks * 64 + lk * 16;
            bf16x8 bh[4], bl[4];
#pragma unroll
            for (int cf = 0; cf < 4; ++cf) {
                int c = wcol + cf * 16 + lr;
                int off = c * 128 + (kb ^ ((c & 7) << 4));
                bh[cf] = *(bf16x8*)((char*)Whp + off);
                bl[cf] = *(bf16x8*)((char*)Wlp + off);
            }
#pragma unroll
            for (int rf = 0; rf < WR; ++rf) {
                int r = wrow + rf * 16 + lr;
                int off = r * 128 + (kb ^ ((r & 7) << 4));
                bf16x8 ah = *(bf16x8*)((char*)Ah + off);
                bf16x8 al = *(bf16x8*)((char*)Al + off);
#pragma unroll
                for (int cf = 0; cf < 4; ++cf) {
                    acc[rf][cf] = __builtin_amdgcn_mfma_f32_16x16x32_bf16(ah, bh[cf], acc[rf][cf], 0, 0, 0);
                    acc[rf][cf] = __builtin_amdgcn_mfma_f32_16x16x32_bf16(al, bh[cf], acc[rf][cf], 0, 0, 0);
                    acc[rf][cf] = __builtin_amdgcn_mfma_f32_16x16x32_bf16(ah, bl[cf], acc[rf][cf], 0, 0, 0);
                }
            }
        }
    }
    // ---- epilogue: C frag (col=lane&15, row=(lane>>4)*4+reg), scale, bf16 ----
#pragma unroll
    for (int rf = 0; rf < WR; ++rf) {
        long rb = r0 + wrow + rf * 16 + lk * 4;
#pragma unroll
        for (int reg = 0; reg < 4; ++reg) {
            long r = rb + reg;
            if (r < N) {
                float dv = dinv[r];
#pragma unroll
                for (int cf = 0; cf < 4; ++cf) {
                    int c = wcol + cf * 16 + lr;
                    H[r * NCOL + c] = f2bf(dv * acc[rf][cf][reg]);
                }
            }
        }
    }
}

// One wave per node, split halves: lanes 0-31 = even edge, 32-63 = odd edge.
// F=128: lane owns 4 features (u64 gather); F=64: 2 features (u32 gather).
// Tail edges padded with DUMMY index -> zero row (no branches in inner loop).
template <int F, bool RELU>
__global__ __launch_bounds__(256) void k_agg(const unsigned short* __restrict__ H,
                                             const int* __restrict__ row_ptr,
                                             const int* __restrict__ col_idx,
                                             const float* __restrict__ dinv,
                                             const float* __restrict__ bias,
                                             float* __restrict__ Y, int N) {
    constexpr int FL = F / 32;          // floats per lane: 4 (F=128) / 2 (F=64)
    int lane = threadIdx.x & 63;
    int node = blockIdx.x * 4 + (threadIdx.x >> 6);
    if (node >= N) return;
    const int half = lane >> 5, hl = lane & 31;
    const int DUMMY = (F == 128) ? N : 2 * N;   // both map to the zero row

    float acc[FL];
    if constexpr (F == 128) {
        if (half == 0) {
            uint64_t u = *(const uint64_t*)&H[(size_t)node * 128 + hl * 4];
            acc[0] = bflo((uint32_t)u);         acc[1] = bfhi((uint32_t)u);
            acc[2] = bflo((uint32_t)(u >> 32)); acc[3] = bfhi((uint32_t)(u >> 32));
        } else { acc[0] = acc[1] = acc[2] = acc[3] = 0.f; }
    } else {
        if (half == 0) {
            uint32_t u = *(const uint32_t*)&H[(size_t)node * 64 + hl * 2];
            acc[0] = bflo(u); acc[1] = bfhi(u);
        } else { acc[0] = acc[1] = 0.f; }
    }

    int start = row_ptr[node], end = row_ptr[node + 1];
    for (int base = start; base < end; base += 64) {
        int idx = DUMMY;
        if (base + lane < end) idx = col_idx[base + lane];
        int cnt = min(64, end - base);
        for (int j = 0; j < cnt; j += 8) {      // 8 edges per iter (2 per pass)
            int s0 = __shfl(idx, j + half);
            int s1 = __shfl(idx, j + 2 + half);
            int s2 = __shfl(idx, j + 4 + half);
            int s3 = __shfl(idx, j + 6 + half);
            if constexpr (F == 128) {
                uint64_t u0 = *(const uint64_t*)&H[(size_t)s0 * 128 + hl * 4];
                uint64_t u1 = *(const uint64_t*)&H[(size_t)s1 * 128 + hl * 4];
                uint64_t u2 = *(const uint64_t*)&H[(size_t)s2 * 128 + hl * 4];
                uint64_t u3 = *(const uint64_t*)&H[(size_t)s3 * 128 + hl * 4];
                acc[0] += bflo((uint32_t)u0);         acc[1] += bfhi((uint32_t)u0);
                acc[2] += bflo((uint32_t)(u0 >> 32)); acc[3] += bfhi((uint32_t)(u0 >> 32));
                acc[0] += bflo((uint32_t)u1);         acc[1] += bfhi((uint32_t)u1);
                acc[2] += bflo((uint32_t)(u1 >> 32)); acc[3] += bfhi((uint32_t)(u1 >> 32));
                acc[0] += bflo((uint32_t)u2);         acc[1] += bfhi((uint32_t)u2);
                acc[2] += bflo((uint32_t)(u2 >> 32)); acc[3] += bfhi((uint32_t)(u2 >> 32));
                acc[0] += bflo((uint32_t)u3);         acc[1] += bfhi((uint32_t)u3);
                acc[2] += bflo((uint32_t)(u3 >> 32)); acc[3] += bfhi((uint32_t)(u3 >> 32));
            } else {
                uint32_t u0 = *(const uint32_t*)&H[(size_t)s0 * 64 + hl * 2];
                uint32_t u1 = *(const uint32_t*)&H[(size_t)s1 * 64 + hl * 2];
                uint32_t u2 = *(const uint32_t*)&H[(size_t)s2 * 64 + hl * 2];
                uint32_t u3 = *(const uint32_t*)&H[(size_t)s3 * 64 + hl * 2];
                acc[0] += bflo(u0); acc[1] += bfhi(u0);
                acc[0] += bflo(u1); acc[1] += bfhi(u1);
                acc[0] += bflo(u2); acc[1] += bfhi(u2);
                acc[0] += bflo(u3); acc[1] += bfhi(u3);
            }
        }
    }

    // combine halves: lane<32 gets lane+32's partial, writes result
    float part[FL];
#pragma unroll
    for (int f = 0; f < FL; ++f) part[f] = __shfl_xor(acc[f], 32);
    if (half == 0) {
        float dv = dinv[node];
        if constexpr (F == 128) {
            float4 b = *(const float4*)&bias[hl * 4];
            float4 o;
            o.x = dv * (acc[0] + part[0]) + b.x;
            o.y = dv * (acc[1] + part[1]) + b.y;
            o.z = dv * (acc[2] + part[2]) + b.z;
            o.w = dv * (acc[3] + part[3]) + b.w;
            if (RELU) {
                o.x = fmaxf(o.x, 0.f); o.y = fmaxf(o.y, 0.f);
                o.z = fmaxf(o.z, 0.f); o.w = fmaxf(o.w, 0.f);
            }
            *(float4*)&Y[(size_t)node * 128 + hl * 4] = o;
        } else {
            float2 b = *(const float2*)&bias[hl * 2];
            float2 o;
            o.x = dv * (acc[0] + part[0]) + b.x;
            o.y = dv * (acc[1] + part[1]) + b.y;
            if (RELU) { o.x = fmaxf(o.x, 0.f); o.y = fmaxf(o.y, 0.f); }
            *(float2*)&Y[(size_t)node * 64 + hl * 2] = o;
        }
    }
}

extern "C" void kernel_launch(void* const* d_in, const int* in_sizes, int n_in,
                              void* d_out, int out_size, void* d_ws, size_t ws_size,
                              hipStream_t stream) {
    const float* x  = (const float*)d_in[0];
    const int* eidx = (const int*)d_in[1];
    const float* W0 = (const float*)d_in[2];
    const float* b0 = (const float*)d_in[3];
    const float* W1 = (const float*)d_in[4];
    const float* b1 = (const float*)d_in[5];
    const float* W2 = (const float*)d_in[6];
    const float* b2 = (const float*)d_in[7];
    float* out = (float*)d_out;

    const int N = in_sizes[0] / 128;
    const int E = in_sizes[1] / 2;
    const int* srcp = eidx;
    const int* dstp = eidx + E;

    const int NBIN   = (N + BINW - 1) / BINW;       // 391 for N=100000
    const int NCHUNK = (E + CE - 1) / CE;           // 391 for E=1.6M

    char* p = (char*)d_ws;
    auto take = [&](size_t bytes) {
        char* r = p;
        p += (bytes + 255) & ~(size_t)255;
        return r;
    };
    int*            cnt     = (int*)take((size_t)NCHUNK * NBIN * 4);
    int*            off_cb  = (int*)take((size_t)NCHUNK * NBIN * 4);
    int*            tot     = (int*)take((size_t)NBIN * 4);
    int*            bin_off = (int*)take((size_t)(NBIN + 1) * 4);
    unsigned int*   bpack   = (unsigned int*)take((size_t)E * 4);
    int*            row_ptr = (int*)take((size_t)(N + 1) * 4);
    float*          dinv    = (float*)take((size_t)N * 4);
    int*            col_idx = (int*)take((size_t)E * 4);
    unsigned short* hbuf    = (unsigned short*)take((size_t)(N + 1) * 128 * 2);
    float*          ybuf    = (float*)take((size_t)N * 128 * 4);
    unsigned short* wt0     = (unsigned short*)take((size_t)2 * 16384 * 2);
    unsigned short* wt1     = (unsigned short*)take((size_t)2 * 16384 * 2);
    unsigned short* wt2     = (unsigned short*)take((size_t)2 * 8192 * 2);

    // ---- CSR build (no memsets, no global atomics) ----
    k_binhist<<<NCHUNK, 256, NBIN * 4, stream>>>(dstp, cnt, NBIN, E);
    k_prepw<<<160, 256, 0, stream>>>(W0, W1, W2, wt0, wt1, wt2);
    k_colscan<<<NBIN, 256, 0, stream>>>(cnt, off_cb, tot, NBIN, NCHUNK);
    k_binoff<<<1, 512, 0, stream>>>(tot, bin_off, row_ptr,
                                    hbuf + (size_t)N * 128, NBIN, N, E);
    k_binscatter<<<NCHUNK, 256, NBIN * 4, stream>>>(srcp, dstp, off_cb, bin_off,
                                                    bpack, NBIN, E);
    k_bindeg<<<NBIN, 256, 0, stream>>>(bpack, bin_off, row_ptr, dinv, N);
    k_csr<<<NBIN, 256, 0, stream>>>(bpack, bin_off, row_ptr, col_idx, N);

    int gemm_grid = (N + 127) / 128;
    int agg_grid  = (N + 3) / 4;

    // layer 0: h' = dinv*(x@W0) ; y = dinv*(sum h') + b0 ; relu
    k_gemm_mfma<128><<<gemm_grid, 256, 0, stream>>>(x, wt0, dinv, hbuf, N);
    k_agg<128, true><<<agg_grid, 256, 0, stream>>>(hbuf, row_ptr, col_idx,
                                                   dinv, b0, ybuf, N);
    // layer 1
    k_gemm_mfma<128><<<gemm_grid, 256, 0, stream>>>(ybuf, wt1, dinv, hbuf, N);
    k_agg<128, true><<<agg_grid, 256, 0, stream>>>(hbuf, row_ptr, col_idx,
                                                   dinv, b1, ybuf, N);
    // layer 2 (64-wide, no relu, straight to d_out)
    k_gemm_mfma<64><<<gemm_grid, 256, 0, stream>>>(ybuf, wt2, dinv, hbuf, N);
    k_agg<64, false><<<agg_grid, 256, 0, stream>>>(hbuf, row_ptr, col_idx,
                                                   dinv, b2, out, N);
}

// Round 9
// 366.867 us; speedup vs baseline: 1.3212x; 1.0764x over previous
//
#include <hip/hip_runtime.h>
#include <hip/hip_bf16.h>
#include <stdint.h>

// ---------------------------------------------------------------------------
// GCN forward: 3 layers of  out = Ahat * (X @ W) + b, relu between layers.
// Factored normalization: out[d] = dinv[d]*( sum_{s in in(d)} H'[s] + H'[d] ) + b
// where H'[i] = bf16( dinv[i] * (A@W)[i] ).
// Activations Y between layers stored BF16 (halves agg writes + GEMM A-reads;
// lets GEMM drop the A hi/lo split: 2 MFMA per tile instead of 3).
// GEMM: MFMA bf16; W always hi/lo split (~f32 weight precision); A split
// hi/lo only for layer 0 (f32 input x).
// CSR build: deterministic two-level counting sort, zero global atomics.
// Aggregation: wave-per-node, QUARTER/OCTAL-wave u128 gather (4 or 8 edges
// per VMEM instr), zero-row padding, f32 accum, shfl_xor cross-slice combine.
// ---------------------------------------------------------------------------

typedef __attribute__((ext_vector_type(8))) short bf16x8;
typedef __attribute__((ext_vector_type(4))) float f32x4;

__device__ __forceinline__ float bflo(uint32_t u) { return __uint_as_float(u << 16); }
__device__ __forceinline__ float bfhi(uint32_t u) { return __uint_as_float(u & 0xffff0000u); }
__device__ __forceinline__ unsigned short f2bf(float f) {
    uint32_t x = __float_as_uint(f);
    return (unsigned short)((x + 0x7fffu + ((x >> 16) & 1u)) >> 16);
}

#define CE   4096   // edges per chunk
#define BINW 256    // nodes per bin

// per-chunk per-bin histogram (LDS only; fully overwrites cnt -> no memset)
__global__ __launch_bounds__(256) void k_binhist(const int* __restrict__ dst,
                                                 int* __restrict__ cnt,
                                                 int NBIN, int E) {
    extern __shared__ int h[];
    int c = blockIdx.x, base = c * CE;
    for (int i = threadIdx.x; i < NBIN; i += 256) h[i] = 0;
    __syncthreads();
    for (int i = 0; i < CE; i += 256) {
        int e = base + i + threadIdx.x;
        if (e < E) atomicAdd(&h[dst[e] >> 8], 1);
    }
    __syncthreads();
    for (int i = threadIdx.x; i < NBIN; i += 256) cnt[c * NBIN + i] = h[i];
}

// per-bin exclusive scan over chunks: off_cb[c][b], tot[b]
__global__ __launch_bounds__(256) void k_colscan(const int* __restrict__ cnt,
                                                 int* __restrict__ off_cb,
                                                 int* __restrict__ tot,
                                                 int NBIN, int NCHUNK) {
    __shared__ int part[256];
    int b = blockIdx.x, t = threadIdx.x;
    int K = (NCHUNK + 255) >> 8;
    int c0 = t * K;
    int vals[16];                       // K <= 16 (E <= 16.7M)
    int s = 0;
    for (int k = 0; k < K; ++k) {
        int c = c0 + k;
        int v = (c < NCHUNK) ? cnt[c * NBIN + b] : 0;
        vals[k] = s;                    // thread-local exclusive prefix
        s += v;
    }
    part[t] = s;
    __syncthreads();
    for (int off = 1; off < 256; off <<= 1) {
        int x = (t >= off) ? part[t - off] : 0;
        __syncthreads();
        part[t] += x;
        __syncthreads();
    }
    int run = (t == 0) ? 0 : part[t - 1];
    for (int k = 0; k < K; ++k) {
        int c = c0 + k;
        if (c < NCHUNK) off_cb[c * NBIN + b] = run + vals[k];
    }
    if (t == 255) tot[b] = part[255];
}

// scan bin totals -> bin_off; also zero agg dummy row, row_ptr[N]=E
__global__ __launch_bounds__(512) void k_binoff(const int* __restrict__ tot,
                                                int* __restrict__ bin_off,
                                                int* __restrict__ row_ptr,
                                                unsigned short* __restrict__ hzero,
                                                int NBIN, int N, int E) {
    __shared__ int part[512];
    int t = threadIdx.x;
    int v = (t < NBIN) ? tot[t] : 0;
    part[t] = v;
    __syncthreads();
    for (int off = 1; off < 512; off <<= 1) {
        int x = (t >= off) ? part[t - off] : 0;
        __syncthreads();
        part[t] += x;
        __syncthreads();
    }
    if (t < NBIN) bin_off[t] = part[t] - v;     // exclusive
    if (t == 0) { bin_off[NBIN] = E; row_ptr[N] = E; }
    if (t < 16) { uint4 z; z.x = z.y = z.z = z.w = 0; ((uint4*)hzero)[t] = z; }
}

// scatter edges into bin-sorted order at precomputed slots (LDS cursors only).
// pack = (d & 255) << 24 | src   (src < 2^24)
__global__ __launch_bounds__(256) void k_binscatter(const int* __restrict__ src,
                                                    const int* __restrict__ dst,
                                                    const int* __restrict__ off_cb,
                                                    const int* __restrict__ bin_off,
                                                    unsigned int* __restrict__ bpack,
                                                    int NBIN, int E) {
    extern __shared__ int lcur[];
    int c = blockIdx.x, base = c * CE;
    for (int i = threadIdx.x; i < NBIN; i += 256)
        lcur[i] = off_cb[c * NBIN + i] + bin_off[i];
    __syncthreads();
    for (int i = 0; i < CE; i += 256) {
        int e = base + i + threadIdx.x;
        if (e < E) {
            int d = dst[e], s = src[e];
            int pos = atomicAdd(&lcur[d >> 8], 1);
            bpack[pos] = (unsigned)s | ((unsigned)(d & 255) << 24);
        }
    }
}

// block-per-bin: LDS deg histogram + scan -> row_ptr, dinv (no global scan!)
__global__ __launch_bounds__(256) void k_bindeg(const unsigned int* __restrict__ bpack,
                                                const int* __restrict__ bin_off,
                                                int* __restrict__ row_ptr,
                                                float* __restrict__ dinv, int N) {
    __shared__ int h[256];
    __shared__ int part[256];
    int b = blockIdx.x, t = threadIdx.x;
    int lo = b * BINW;
    h[t] = 0;
    __syncthreads();
    int s0 = bin_off[b], s1 = bin_off[b + 1];
    for (int i = s0 + t; i < s1; i += 256)
        atomicAdd(&h[bpack[i] >> 24], 1);
    __syncthreads();
    int dg = h[t];
    part[t] = dg;
    __syncthreads();
    for (int off = 1; off < 256; off <<= 1) {
        int x = (t >= off) ? part[t - off] : 0;
        __syncthreads();
        part[t] += x;
        __syncthreads();
    }
    if (lo + t < N) {
        row_ptr[lo + t] = s0 + part[t] - dg;    // bin start + in-bin excl prefix
        dinv[lo + t] = rsqrtf((float)(dg + 1)); // +1 self-loop
    }
}

// block-per-bin CSR fill: writes confined to the bin's col_idx span
__global__ __launch_bounds__(256) void k_csr(const unsigned int* __restrict__ bpack,
                                             const int* __restrict__ bin_off,
                                             const int* __restrict__ row_ptr,
                                             int* __restrict__ col_idx, int N) {
    __shared__ int lcur[256];
    int b = blockIdx.x, t = threadIdx.x;
    int lo = b * BINW;
    lcur[t] = (lo + t < N) ? row_ptr[lo + t] : 0;
    __syncthreads();
    int s0 = bin_off[b], s1 = bin_off[b + 1];
    for (int i = s0 + t; i < s1; i += 256) {
        unsigned pk = bpack[i];
        int pos = atomicAdd(&lcur[pk >> 24], 1);
        col_idx[pos] = (int)(pk & 0xFFFFFFu);
    }
}

// W [K][M] f32 -> Wt_hi[c][k], Wt_lo[c][k] bf16 (transposed, hi plane then lo)
__global__ __launch_bounds__(256) void k_prepw(const float* __restrict__ W0,
                                               const float* __restrict__ W1,
                                               const float* __restrict__ W2,
                                               unsigned short* __restrict__ wt0,
                                               unsigned short* __restrict__ wt1,
                                               unsigned short* __restrict__ wt2) {
    int id = blockIdx.x * 256 + threadIdx.x;
    const float* Wsrc;
    unsigned short* dst;
    int t, M, plane;
    if (id < 16384)      { t = id;         Wsrc = W0; dst = wt0; M = 128; plane = 16384; }
    else if (id < 32768) { t = id - 16384; Wsrc = W1; dst = wt1; M = 128; plane = 16384; }
    else if (id < 40960) { t = id - 32768; Wsrc = W2; dst = wt2; M = 64;  plane = 8192;  }
    else return;
    int k = (M == 128) ? (t >> 7) : (t >> 6);
    int c = (M == 128) ? (t & 127) : (t & 63);
    float v = Wsrc[k * M + c];
    unsigned short hi = f2bf(v);
    float lov = v - bflo((uint32_t)hi);
    dst[c * 128 + k]         = hi;
    dst[plane + c * 128 + k] = f2bf(lov);
}

// H[r,:] = bf16( dinv[r] * (A[r,:] @ W) ) via MFMA.
// BF16A=false: A f32 [N,128], hi/lo split in staging, 3 MFMA per tile.
// BF16A=true : A bf16 [N,128], single plane, 2 MFMA per tile.
// W always hi/lo bf16 [NCOL][128] x2. Tile 128 rows x NCOL, K-tiled by 64.
template <int NCOL, bool BF16A>
__global__ __launch_bounds__(256) void k_gemm_mfma(
    const void* __restrict__ Av, const unsigned short* __restrict__ Wt,
    const float* __restrict__ dinv, unsigned short* __restrict__ H, int N) {
    constexpr int K = 128, KT = 64;
    constexpr int A_SH = 128 * KT;        // shorts per A plane
    constexpr int APL = BF16A ? 1 : 2;
    constexpr int W_PLANE = NCOL * KT;
    __shared__ __align__(16) unsigned short sm[APL * A_SH + 2 * W_PLANE];
    unsigned short* Ah  = sm;
    unsigned short* Al  = sm + A_SH;                 // only used if !BF16A
    unsigned short* Whp = sm + APL * A_SH;
    unsigned short* Wlp = sm + APL * A_SH + W_PLANE;

    const int tid = threadIdx.x;
    const long r0 = (long)blockIdx.x * 128;
    const int w = tid >> 6, l = tid & 63;
    const int lr = l & 15, lk = l >> 4;
    constexpr int WR = (NCOL == 128) ? 4 : 2;          // 16-row frags per wave
    const int wrow = (NCOL == 128) ? (w >> 1) * 64 : w * 32;
    const int wcol = (NCOL == 128) ? (w & 1) * 64 : 0;

    f32x4 acc[WR][4];
#pragma unroll
    for (int i = 0; i < WR; ++i)
#pragma unroll
        for (int j = 0; j < 4; ++j) acc[i][j] = (f32x4){0.f, 0.f, 0.f, 0.f};

    for (int kt = 0; kt < 2; ++kt) {
        if (kt) __syncthreads();           // previous compute done
        // ---- stage A tile: 128 rows x 64 k, swizzled ----
#pragma unroll
        for (int it = 0; it < 4; ++it) {
            int id = it * 256 + tid;
            int r = id >> 3, kc = id & 7;   // 8 chunks of 8 elems per row
            long gr = r0 + r;
            if (gr >= N) gr = N - 1;
            int boff = r * 128 + ((kc * 16) ^ ((r & 7) << 4));
            if constexpr (BF16A) {
                const unsigned short* ap =
                    (const unsigned short*)Av + gr * K + kt * KT + kc * 8;
                *(bf16x8*)((char*)Ah + boff) = *(const bf16x8*)ap;
            } else {
                const float* ap = (const float*)Av + gr * K + kt * KT + kc * 8;
                float4 v0 = *(const float4*)ap;
                float4 v1 = *(const float4*)(ap + 4);
                float vv[8] = {v0.x, v0.y, v0.z, v0.w, v1.x, v1.y, v1.z, v1.w};
                union { unsigned short u[8]; bf16x8 v; } ph, pl;
#pragma unroll
                for (int j = 0; j < 8; ++j) {
                    unsigned short h = f2bf(vv[j]);
                    ph.u[j] = h;
                    pl.u[j] = f2bf(vv[j] - bflo((uint32_t)h));
                }
                *(bf16x8*)((char*)Ah + boff) = ph.v;
                *(bf16x8*)((char*)Al + boff) = pl.v;
            }
        }
        // ---- stage W tile: NCOL rows x 64 k, hi+lo, swizzled ----
#pragma unroll
        for (int it = 0; it < NCOL / 32; ++it) {
            int id = it * 256 + tid;
            int c = id >> 3, kc = id & 7;
            const unsigned short* wp = &Wt[c * K + kt * KT + kc * 8];
            bf16x8 vh = *(const bf16x8*)wp;
            bf16x8 vl = *(const bf16x8*)(wp + NCOL * K);
            int boff = c * 128 + ((kc * 16) ^ ((c & 7) << 4));
            *(bf16x8*)((char*)Whp + boff) = vh;
            *(bf16x8*)((char*)Wlp + boff) = vl;
        }
        __syncthreads();
        // ---- compute: 2 k-steps of 32 ----
#pragma unroll
        for (int ks = 0; ks < 2; ++ks) {
            int kb = ks * 64 + lk * 16;
            bf16x8 bh[4], bl[4];
#pragma unroll
            for (int cf = 0; cf < 4; ++cf) {
                int c = wcol + cf * 16 + lr;
                int off = c * 128 + (kb ^ ((c & 7) << 4));
                bh[cf] = *(bf16x8*)((char*)Whp + off);
                bl[cf] = *(bf16x8*)((char*)Wlp + off);
            }
#pragma unroll
            for (int rf = 0; rf < WR; ++rf) {
                int r = wrow + rf * 16 + lr;
                int off = r * 128 + (kb ^ ((r & 7) << 4));
                bf16x8 ah = *(bf16x8*)((char*)Ah + off);
                if constexpr (BF16A) {
#pragma unroll
                    for (int cf = 0; cf < 4; ++cf) {
                        acc[rf][cf] = __builtin_amdgcn_mfma_f32_16x16x32_bf16(ah, bh[cf], acc[rf][cf], 0, 0, 0);
                        acc[rf][cf] = __builtin_amdgcn_mfma_f32_16x16x32_bf16(ah, bl[cf], acc[rf][cf], 0, 0, 0);
                    }
                } else {
                    bf16x8 al = *(bf16x8*)((char*)Al + off);
#pragma unroll
                    for (int cf = 0; cf < 4; ++cf) {
                        acc[rf][cf] = __builtin_amdgcn_mfma_f32_16x16x32_bf16(ah, bh[cf], acc[rf][cf], 0, 0, 0);
                        acc[rf][cf] = __builtin_amdgcn_mfma_f32_16x16x32_bf16(al, bh[cf], acc[rf][cf], 0, 0, 0);
                        acc[rf][cf] = __builtin_amdgcn_mfma_f32_16x16x32_bf16(ah, bl[cf], acc[rf][cf], 0, 0, 0);
                    }
                }
            }
        }
    }
    // ---- epilogue: C frag (col=lane&15, row=(lane>>4)*4+reg), scale, bf16 ----
#pragma unroll
    for (int rf = 0; rf < WR; ++rf) {
        long rb = r0 + wrow + rf * 16 + lk * 4;
#pragma unroll
        for (int reg = 0; reg < 4; ++reg) {
            long r = rb + reg;
            if (r < N) {
                float dv = dinv[r];
#pragma unroll
                for (int cf = 0; cf < 4; ++cf) {
                    int c = wcol + cf * 16 + lr;
                    H[r * NCOL + c] = f2bf(dv * acc[rf][cf][reg]);
                }
            }
        }
    }
}

// One wave per node. Row of F bf16 = F/8 lanes x 16B -> EPW = 64/(F/8) edges
// per VMEM instruction (4 for F=128, 8 for F=64). Slice partials combine via
// shfl_xor. Tail edges padded with DUMMY -> zero row (no inner branches).
// OUTBF16: write Y as bf16 (layers 0/1); else f32 (final layer).
template <int F, bool RELU, bool OUTBF16>
__global__ __launch_bounds__(256) void k_agg(const unsigned short* __restrict__ H,
                                             const int* __restrict__ row_ptr,
                                             const int* __restrict__ col_idx,
                                             const float* __restrict__ dinv,
                                             const float* __restrict__ bias,
                                             void* __restrict__ Yv, int N) {
    constexpr int LPR = F / 8;          // lanes per row (16 or 8)
    constexpr int EPW = 64 / LPR;       // edges per wave instr (4 or 8)
    int lane = threadIdx.x & 63;
    int node = blockIdx.x * 4 + (threadIdx.x >> 6);
    if (node >= N) return;
    const int q  = lane / LPR;          // edge slot within group
    const int ql = lane % LPR;          // 16B slice within row
    const int DUMMY = (F == 128) ? N : 2 * N;   // both map to the zero row

    float acc[8];
#pragma unroll
    for (int f = 0; f < 8; ++f) acc[f] = 0.f;
    if (q == 0) {                        // self term H'[node]
        uint4 u = *((const uint4*)(H + (size_t)node * F) + ql);
        acc[0] = bflo(u.x); acc[1] = bfhi(u.x);
        acc[2] = bflo(u.y); acc[3] = bfhi(u.y);
        acc[4] = bflo(u.z); acc[5] = bfhi(u.z);
        acc[6] = bflo(u.w); acc[7] = bfhi(u.w);
    }

#define ACC8(u)                                                         \
    acc[0] += bflo(u.x); acc[1] += bfhi(u.x);                           \
    acc[2] += bflo(u.y); acc[3] += bfhi(u.y);                           \
    acc[4] += bflo(u.z); acc[5] += bfhi(u.z);                           \
    acc[6] += bflo(u.w); acc[7] += bfhi(u.w);

    int start = row_ptr[node], end = row_ptr[node + 1];
    for (int base = start; base < end; base += 64) {
        int idx = DUMMY;
        if (base + lane < end) idx = col_idx[base + lane];
        int cnt = min(64, end - base);
        int j = 0;
        for (; j + 4 * EPW <= cnt; j += 4 * EPW) {
            int s0 = __shfl(idx, j + q);
            int s1 = __shfl(idx, j + EPW + q);
            int s2 = __shfl(idx, j + 2 * EPW + q);
            int s3 = __shfl(idx, j + 3 * EPW + q);
            uint4 u0 = *((const uint4*)(H + (size_t)s0 * F) + ql);
            uint4 u1 = *((const uint4*)(H + (size_t)s1 * F) + ql);
            uint4 u2 = *((const uint4*)(H + (size_t)s2 * F) + ql);
            uint4 u3 = *((const uint4*)(H + (size_t)s3 * F) + ql);
            ACC8(u0); ACC8(u1); ACC8(u2); ACC8(u3);
        }
        if (j + 2 * EPW <= cnt) {
            int s0 = __shfl(idx, j + q);
            int s1 = __shfl(idx, j + EPW + q);
            uint4 u0 = *((const uint4*)(H + (size_t)s0 * F) + ql);
            uint4 u1 = *((const uint4*)(H + (size_t)s1 * F) + ql);
            ACC8(u0); ACC8(u1);
            j += 2 * EPW;
        }
        for (; j < cnt; j += EPW) {
            int s = __shfl(idx, j + q);
            uint4 u = *((const uint4*)(H + (size_t)s * F) + ql);
            ACC8(u);
        }
    }
#undef ACC8

    // combine slice partials across edge slots
#pragma unroll
    for (int f = 0; f < 8; ++f) {
        if constexpr (F == 64) acc[f] += __shfl_xor(acc[f], 8);
        acc[f] += __shfl_xor(acc[f], 16);
        acc[f] += __shfl_xor(acc[f], 32);
    }

    float dv = dinv[node];
    if constexpr (OUTBF16) {
        if (q == 0) {
            float4 b0 = *(const float4*)&bias[ql * 8];
            float4 b1 = *(const float4*)&bias[ql * 8 + 4];
            float y[8];
            y[0] = dv * acc[0] + b0.x; y[1] = dv * acc[1] + b0.y;
            y[2] = dv * acc[2] + b0.z; y[3] = dv * acc[3] + b0.w;
            y[4] = dv * acc[4] + b1.x; y[5] = dv * acc[5] + b1.y;
            y[6] = dv * acc[6] + b1.z; y[7] = dv * acc[7] + b1.w;
            uint4 o;
            unsigned* ow = (unsigned*)&o;
#pragma unroll
            for (int k = 0; k < 4; ++k) {
                float a0 = y[2 * k], a1 = y[2 * k + 1];
                if (RELU) { a0 = fmaxf(a0, 0.f); a1 = fmaxf(a1, 0.f); }
                ow[k] = (unsigned)f2bf(a0) | ((unsigned)f2bf(a1) << 16);
            }
            *((uint4*)((unsigned short*)Yv + (size_t)node * F) + ql) = o;
        }
    } else {
        if (q < 2) {
            int fb = ql * 8 + q * 4;
            float4 b = *(const float4*)&bias[fb];
            float4 o;
            o.x = dv * acc[q * 4 + 0] + b.x;
            o.y = dv * acc[q * 4 + 1] + b.y;
            o.z = dv * acc[q * 4 + 2] + b.z;
            o.w = dv * acc[q * 4 + 3] + b.w;
            if (RELU) {
                o.x = fmaxf(o.x, 0.f); o.y = fmaxf(o.y, 0.f);
                o.z = fmaxf(o.z, 0.f); o.w = fmaxf(o.w, 0.f);
            }
            *(float4*)((float*)Yv + (size_t)node * F + fb) = o;
        }
    }
}

extern "C" void kernel_launch(void* const* d_in, const int* in_sizes, int n_in,
                              void* d_out, int out_size, void* d_ws, size_t ws_size,
                              hipStream_t stream) {
    const float* x  = (const float*)d_in[0];
    const int* eidx = (const int*)d_in[1];
    const float* W0 = (const float*)d_in[2];
    const float* b0 = (const float*)d_in[3];
    const float* W1 = (const float*)d_in[4];
    const float* b1 = (const float*)d_in[5];
    const float* W2 = (const float*)d_in[6];
    const float* b2 = (const float*)d_in[7];
    float* out = (float*)d_out;

    const int N = in_sizes[0] / 128;
    const int E = in_sizes[1] / 2;
    const int* srcp = eidx;
    const int* dstp = eidx + E;

    const int NBIN   = (N + BINW - 1) / BINW;       // 391 for N=100000
    const int NCHUNK = (E + CE - 1) / CE;           // 391 for E=1.6M

    char* p = (char*)d_ws;
    auto take = [&](size_t bytes) {
        char* r = p;
        p += (bytes + 255) & ~(size_t)255;
        return r;
    };
    int*            cnt     = (int*)take((size_t)NCHUNK * NBIN * 4);
    int*            off_cb  = (int*)take((size_t)NCHUNK * NBIN * 4);
    int*            tot     = (int*)take((size_t)NBIN * 4);
    int*            bin_off = (int*)take((size_t)(NBIN + 1) * 4);
    unsigned int*   bpack   = (unsigned int*)take((size_t)E * 4);
    int*            row_ptr = (int*)take((size_t)(N + 1) * 4);
    float*          dinv    = (float*)take((size_t)N * 4);
    int*            col_idx = (int*)take((size_t)E * 4);
    unsigned short* hbuf    = (unsigned short*)take((size_t)(N + 1) * 128 * 2);
    unsigned short* ybuf    = (unsigned short*)take((size_t)N * 128 * 2);
    unsigned short* wt0     = (unsigned short*)take((size_t)2 * 16384 * 2);
    unsigned short* wt1     = (unsigned short*)take((size_t)2 * 16384 * 2);
    unsigned short* wt2     = (unsigned short*)take((size_t)2 * 8192 * 2);

    // ---- CSR build (no memsets, no global atomics) ----
    k_binhist<<<NCHUNK, 256, NBIN * 4, stream>>>(dstp, cnt, NBIN, E);
    k_prepw<<<160, 256, 0, stream>>>(W0, W1, W2, wt0, wt1, wt2);
    k_colscan<<<NBIN, 256, 0, stream>>>(cnt, off_cb, tot, NBIN, NCHUNK);
    k_binoff<<<1, 512, 0, stream>>>(tot, bin_off, row_ptr,
                                    hbuf + (size_t)N * 128, NBIN, N, E);
    k_binscatter<<<NCHUNK, 256, NBIN * 4, stream>>>(srcp, dstp, off_cb, bin_off,
                                                    bpack, NBIN, E);
    k_bindeg<<<NBIN, 256, 0, stream>>>(bpack, bin_off, row_ptr, dinv, N);
    k_csr<<<NBIN, 256, 0, stream>>>(bpack, bin_off, row_ptr, col_idx, N);

    int gemm_grid = (N + 127) / 128;
    int agg_grid  = (N + 3) / 4;

    // layer 0: h' = dinv*(x@W0) ; y = bf16( relu(dinv*(sum h') + b0) )
    k_gemm_mfma<128, false><<<gemm_grid, 256, 0, stream>>>(x, wt0, dinv, hbuf, N);
    k_agg<128, true, true><<<agg_grid, 256, 0, stream>>>(hbuf, row_ptr, col_idx,
                                                         dinv, b0, ybuf, N);
    // layer 1 (bf16 A -> 2-MFMA GEMM)
    k_gemm_mfma<128, true><<<gemm_grid, 256, 0, stream>>>(ybuf, wt1, dinv, hbuf, N);
    k_agg<128, true, true><<<agg_grid, 256, 0, stream>>>(hbuf, row_ptr, col_idx,
                                                         dinv, b1, ybuf, N);
    // layer 2 (64-wide, no relu, f32 straight to d_out)
    k_gemm_mfma<64, true><<<gemm_grid, 256, 0, stream>>>(ybuf, wt2, dinv, hbuf, N);
    k_agg<64, false, false><<<agg_grid, 256, 0, stream>>>(hbuf, row_ptr, col_idx,
                                                          dinv, b2, out, N);
}